// Round 12
// baseline (319.046 us; speedup 1.0000x reference)
//
#include <hip/hip_runtime.h>
#include <hip/hip_bf16.h>
#include <stdint.h>

#define D 128
#define BSH 8                 // bucket = 256 nodes
#define BKN 256               // nodes per bucket
#define TILE 4096             // edges per bin_edges block
#define CAPB 5376             // per-bucket slot capacity (mean ~4096, sd ~64, 20-sigma headroom)

typedef __attribute__((ext_vector_type(8))) short short8;
typedef __attribute__((ext_vector_type(4))) float f32x4;

typedef __attribute__((address_space(1))) const void gvoid;
typedef __attribute__((address_space(3))) void lvoid;

__device__ inline float bf16lo(uint32_t u){ return __uint_as_float(u << 16); }
__device__ inline float bf16hi(uint32_t u){ return __uint_as_float(u & 0xffff0000u); }
__device__ inline unsigned short f2bf(float f){
    union { __hip_bfloat16 h; unsigned short u; } cvt;
    cvt.h = __float2bfloat16(f);
    return cvt.u;
}

#define ACC8(q) \
    acc[0] += bf16lo(q.x); acc[1] += bf16hi(q.x); \
    acc[2] += bf16lo(q.y); acc[3] += bf16hi(q.y); \
    acc[4] += bf16lo(q.z); acc[5] += bf16hi(q.z); \
    acc[6] += bf16lo(q.w); acc[7] += bf16hi(q.w);

#define ACC4(q) \
    acc[0] += bf16lo(q.x); acc[1] += bf16hi(q.x); \
    acc[2] += bf16lo(q.y); acc[3] += bf16hi(q.y);

// ---------- binned edge scatter: direct 2-pass, padded per-bucket regions ----------
__global__ __launch_bounds__(256) void bin_edges(
    const int* __restrict__ src, const int* __restrict__ dst,
    int* __restrict__ bfill, uint32_t* __restrict__ binbuf, int E, int nbk)
{
    __shared__ int hist[400];
    __shared__ int cur[400];
    int t = threadIdx.x;
    int tile0 = blockIdx.x * TILE;
    int cnt = min(TILE, E - tile0);

    for (int i = t; i < nbk; i += 256) hist[i] = 0;
    __syncthreads();
    for (int i = t; i < cnt; i += 256)
        atomicAdd(&hist[dst[tile0 + i] >> BSH], 1);
    __syncthreads();
    for (int i = t; i < nbk; i += 256){
        int h = hist[i];
        int base = h ? atomicAdd(&bfill[i], h) : 0;
        cur[i] = i * CAPB + base;
    }
    __syncthreads();
    for (int i = t; i < cnt; i += 256){
        int d = dst[tile0 + i];
        int b = d >> BSH;
        int p = atomicAdd(&cur[b], 1);
        binbuf[p] = (uint32_t)src[tile0 + i] | ((uint32_t)(d & (BKN - 1)) << 17);
    }
}

// one block per 256-node bucket: histogram -> scan -> roff/rend + LDS csr scatter,
// per-node SORT BY SRC (gather-locality: concurrent lanes walk the table in lockstep),
// then coalesced LDS->global csr copy.
__global__ __launch_bounds__(256) void fill_bucket(
    const uint32_t* __restrict__ binbuf, const int* __restrict__ bcnt,
    int* __restrict__ roff, int* __restrict__ rend, int* __restrict__ csr, int n, int nbk)
{
    __shared__ int hist[BKN];
    __shared__ int hist2[BKN];
    __shared__ int hb[BKN];
    __shared__ int sc[256];
    __shared__ int csr_l[CAPB];
    int b = blockIdx.x, t = threadIdx.x;
    int e0 = b * CAPB;
    int cnt = bcnt[b];
    int v0 = b << BSH;
    int nv = min(BKN, n - v0);

    hist[t] = 0; hist2[t] = 0;
    __syncthreads();
    for (int e = t; e < cnt; e += 256)
        atomicAdd(&hist[binbuf[e0 + e] >> 17], 1);
    __syncthreads();
    int own = hist[t];
    sc[t] = own;
    __syncthreads();
    for (int o = 1; o < 256; o <<= 1){
        int x = (t >= o) ? sc[t - o] : 0;
        __syncthreads();
        sc[t] += x;
        __syncthreads();
    }
    int ex = sc[t] - own;
    hb[t] = ex;
    if (t < nv){
        roff[v0 + t] = e0 + ex;
        rend[v0 + t] = e0 + ex + own;
    }
    __syncthreads();
    for (int e = t; e < cnt; e += 256){
        uint32_t p = binbuf[e0 + e];
        int local = p >> 17;
        int pos = hb[local] + atomicAdd(&hist2[local], 1);
        csr_l[pos] = (int)(p & 0x1FFFFu);
    }
    __syncthreads();
    // per-node insertion sort by src (segment [ex, ex+own) in csr_l)
    for (int j = ex + 1; j < ex + own; j++){
        int key = csr_l[j];
        int i = j - 1;
        while (i >= ex && csr_l[i] > key){ csr_l[i + 1] = csr_l[i]; i--; }
        csr_l[i + 1] = key;
    }
    __syncthreads();
    for (int e = t; e < cnt; e += 256)
        csr[e0 + e] = csr_l[e];
}

// ---------- weight pre-transpose: WT[j][k] = bf16(Wcat[k][j]), Wcat = [Wl | Wr], NC=2*DOUT cols ----------
__global__ void wt_prep(const float* __restrict__ Wl, const float* __restrict__ Wr,
                        unsigned short* __restrict__ WT, int dout){
    int nc = dout * 2;
    int idx = blockIdx.x * 256 + threadIdx.x;
    if (idx >= nc * 128) return;
    int k = idx & 127, j = idx >> 7;
    float w = (j < dout) ? Wl[k * dout + j] : Wr[k * dout + (j - dout)];
    WT[j * 128 + k] = f2bf(w);
}

// ---------- dense GEMM: ylz = X @ [Wl|Wr] + [0|b]  (M=n, N=NC, K=128) ----------
template<int NC, bool AF32>
__global__ __launch_bounds__(256, 3) void dense_gemm(
    const unsigned short* __restrict__ xb, const float* __restrict__ xf,
    const unsigned short* __restrict__ WT, const float* __restrict__ bias,
    unsigned short* __restrict__ ylz, int n)
{
    constexpr int DOUT = NC / 2;
    __shared__ __align__(16) char As[128 * 256];
    int tid = threadIdx.x, lane = tid & 63, wave = tid >> 6;
    int rbase = blockIdx.x * 128;
    int lrow = lane & 15, lk = (lane >> 4) * 8;
    int colbase = blockIdx.y * 128 + wave * 32;

    short8 bfr[4][2];
    #pragma unroll
    for (int kk = 0; kk < 4; kk++)
        #pragma unroll
        for (int cf = 0; cf < 2; cf++)
            bfr[kk][cf] = *reinterpret_cast<const short8*>(
                WT + (size_t)(colbase + cf * 16 + lrow) * 128 + kk * 32 + lk);

    if constexpr (AF32){
        int cb = (tid & 15) * 16;
        #pragma unroll
        for (int i = 0; i < 8; i++){
            int row = i * 16 + (tid >> 4);
            int grow = min(rbase + row, n - 1);
            const float* p = xf + (size_t)grow * 128 + (cb >> 1);
            float4 f0 = *reinterpret_cast<const float4*>(p);
            float4 f1 = *reinterpret_cast<const float4*>(p + 4);
            uint4 q;
            q.x = (uint32_t)f2bf(f0.x) | ((uint32_t)f2bf(f0.y) << 16);
            q.y = (uint32_t)f2bf(f0.z) | ((uint32_t)f2bf(f0.w) << 16);
            q.z = (uint32_t)f2bf(f1.x) | ((uint32_t)f2bf(f1.y) << 16);
            q.w = (uint32_t)f2bf(f1.z) | ((uint32_t)f2bf(f1.w) << 16);
            *reinterpret_cast<uint4*>(As + row * 256 + (cb ^ ((row & 7) << 4))) = q;
        }
    } else {
        int cb = (lane & 15) * 16;
        #pragma unroll
        for (int i = 0; i < 8; i++){
            int row = i * 16 + (tid >> 4);
            int grow = min(rbase + row, n - 1);
            const unsigned short* gsrc = xb + (size_t)grow * 128 + ((cb ^ ((row & 7) << 4)) >> 1);
            __builtin_amdgcn_global_load_lds(
                (gvoid*)gsrc,
                (lvoid*)(As + (i * 16 + wave * 4) * 256),
                16, 0, 0);
        }
    }
    __syncthreads();

    f32x4 acc[8][2];
    #pragma unroll
    for (int fr = 0; fr < 8; fr++)
        #pragma unroll
        for (int cf = 0; cf < 2; cf++)
            acc[fr][cf] = (f32x4){0.f, 0.f, 0.f, 0.f};

    #pragma unroll
    for (int kk = 0; kk < 4; kk++){
        int cb = kk * 64 + (lane >> 4) * 16;
        #pragma unroll
        for (int fr = 0; fr < 8; fr++){
            int row = fr * 16 + lrow;
            short8 a = *reinterpret_cast<const short8*>(As + row * 256 + (cb ^ ((row & 7) << 4)));
            #pragma unroll
            for (int cf = 0; cf < 2; cf++)
                acc[fr][cf] = __builtin_amdgcn_mfma_f32_16x16x32_bf16(bfr[kk][cf], a, acc[fr][cf], 0, 0, 0);
        }
    }

    float4 bv[2];
    #pragma unroll
    for (int cf = 0; cf < 2; cf++){
        int cg = colbase + cf * 16 + (lane >> 4) * 4;
        bv[cf] = (cg >= DOUT) ? *reinterpret_cast<const float4*>(bias + (cg - DOUT))
                              : (float4){0.f, 0.f, 0.f, 0.f};
    }

    #pragma unroll
    for (int fr = 0; fr < 8; fr++){
        int row = rbase + fr * 16 + lrow;
        if (row < n){
            #pragma unroll
            for (int cf = 0; cf < 2; cf++){
                int cg = colbase + cf * 16 + (lane >> 4) * 4;
                uint2 o;
                o.x = (uint32_t)f2bf(acc[fr][cf][0] + bv[cf].x) |
                      ((uint32_t)f2bf(acc[fr][cf][1] + bv[cf].y) << 16);
                o.y = (uint32_t)f2bf(acc[fr][cf][2] + bv[cf].z) |
                      ((uint32_t)f2bf(acc[fr][cf][3] + bv[cf].w) << 16);
                *reinterpret_cast<uint2*>(ylz + (size_t)row * NC + cg) = o;
            }
        }
    }
}

// ---------- aggregation: h = relu(mean_gather(yl) + z), yl/z in ylz[N][256] ----------
__global__ __launch_bounds__(256, 4) void agg_relu(
    const unsigned short* __restrict__ ylz, const int* __restrict__ roff,
    const int* __restrict__ rend,
    const int* __restrict__ csr, unsigned short* __restrict__ hout, int n)
{
    int grp = threadIdx.x >> 4, li = threadIdx.x & 15;
    int v = blockIdx.x * 16 + grp;
    if (v >= n) return;
    int s0 = roff[v], s1 = rend[v];
    const unsigned short* base = ylz + li * 8;
    float acc[8] = {0.f,0.f,0.f,0.f,0.f,0.f,0.f,0.f};
    int e = s0;
    for (; e + 8 <= s1; e += 8){
        int i0=csr[e],i1=csr[e+1],i2=csr[e+2],i3=csr[e+3];
        int i4=csr[e+4],i5=csr[e+5],i6=csr[e+6],i7=csr[e+7];
        uint4 q0 = *reinterpret_cast<const uint4*>(base + (size_t)i0 * 256);
        uint4 q1 = *reinterpret_cast<const uint4*>(base + (size_t)i1 * 256);
        uint4 q2 = *reinterpret_cast<const uint4*>(base + (size_t)i2 * 256);
        uint4 q3 = *reinterpret_cast<const uint4*>(base + (size_t)i3 * 256);
        uint4 q4 = *reinterpret_cast<const uint4*>(base + (size_t)i4 * 256);
        uint4 q5 = *reinterpret_cast<const uint4*>(base + (size_t)i5 * 256);
        uint4 q6 = *reinterpret_cast<const uint4*>(base + (size_t)i6 * 256);
        uint4 q7 = *reinterpret_cast<const uint4*>(base + (size_t)i7 * 256);
        ACC8(q0) ACC8(q1) ACC8(q2) ACC8(q3) ACC8(q4) ACC8(q5) ACC8(q6) ACC8(q7)
    }
    if (e < s1){
        int last = s1 - 1;
        int i0=csr[e];
        int i1=csr[min(e+1,last)],i2=csr[min(e+2,last)],i3=csr[min(e+3,last)];
        int i4=csr[min(e+4,last)],i5=csr[min(e+5,last)],i6=csr[min(e+6,last)],i7=csr[min(e+7,last)];
        uint4 z4 = make_uint4(0,0,0,0);
        uint4 q0 = *reinterpret_cast<const uint4*>(base + (size_t)i0 * 256);
        uint4 q1 = *reinterpret_cast<const uint4*>(base + (size_t)i1 * 256);
        uint4 q2 = *reinterpret_cast<const uint4*>(base + (size_t)i2 * 256);
        uint4 q3 = *reinterpret_cast<const uint4*>(base + (size_t)i3 * 256);
        uint4 q4 = *reinterpret_cast<const uint4*>(base + (size_t)i4 * 256);
        uint4 q5 = *reinterpret_cast<const uint4*>(base + (size_t)i5 * 256);
        uint4 q6 = *reinterpret_cast<const uint4*>(base + (size_t)i6 * 256);
        uint4 q7 = *reinterpret_cast<const uint4*>(base + (size_t)i7 * 256);
        if (e+1 > last) q1 = z4;
        if (e+2 > last) q2 = z4;
        if (e+3 > last) q3 = z4;
        if (e+4 > last) q4 = z4;
        if (e+5 > last) q5 = z4;
        if (e+6 > last) q6 = z4;
        if (e+7 > last) q7 = z4;
        ACC8(q0) ACC8(q1) ACC8(q2) ACC8(q3) ACC8(q4) ACC8(q5) ACC8(q6) ACC8(q7)
    }
    int d = s1 - s0;
    float inv = (d > 0) ? 1.0f / (float)d : 0.0f;
    uint4 zq = *reinterpret_cast<const uint4*>(ylz + (size_t)v * 256 + 128 + li * 8);
    float z0=bf16lo(zq.x), z1=bf16hi(zq.x), z2=bf16lo(zq.y), z3=bf16hi(zq.y);
    float z4_=bf16lo(zq.z), z5=bf16hi(zq.z), z6=bf16lo(zq.w), z7=bf16hi(zq.w);
    uint4 o;
    o.x = (uint32_t)f2bf(fmaxf(acc[0]*inv+z0,0.f)) | ((uint32_t)f2bf(fmaxf(acc[1]*inv+z1,0.f)) << 16);
    o.y = (uint32_t)f2bf(fmaxf(acc[2]*inv+z2,0.f)) | ((uint32_t)f2bf(fmaxf(acc[3]*inv+z3,0.f)) << 16);
    o.z = (uint32_t)f2bf(fmaxf(acc[4]*inv+z4_,0.f)) | ((uint32_t)f2bf(fmaxf(acc[5]*inv+z5,0.f)) << 16);
    o.w = (uint32_t)f2bf(fmaxf(acc[6]*inv+z6,0.f)) | ((uint32_t)f2bf(fmaxf(acc[7]*inv+z7,0.f)) << 16);
    *reinterpret_cast<uint4*>(hout + (size_t)v * 128 + li * 8) = o;
}

// ---------- final layer aggregation: out = mean_gather(yl2) + z2, fp32 out, ylz[N][128] ----------
__global__ __launch_bounds__(256, 4) void agg_out64(
    const unsigned short* __restrict__ ylz, const int* __restrict__ roff,
    const int* __restrict__ rend,
    const int* __restrict__ csr, float* __restrict__ out, int n)
{
    int grp = threadIdx.x >> 4, li = threadIdx.x & 15;
    int v = blockIdx.x * 16 + grp;
    if (v >= n) return;
    int s0 = roff[v], s1 = rend[v];
    const unsigned short* base = ylz + li * 4;
    float acc[4] = {0.f,0.f,0.f,0.f};
    int e = s0;
    for (; e + 8 <= s1; e += 8){
        int i0=csr[e],i1=csr[e+1],i2=csr[e+2],i3=csr[e+3];
        int i4=csr[e+4],i5=csr[e+5],i6=csr[e+6],i7=csr[e+7];
        uint2 q0 = *reinterpret_cast<const uint2*>(base + (size_t)i0 * 128);
        uint2 q1 = *reinterpret_cast<const uint2*>(base + (size_t)i1 * 128);
        uint2 q2 = *reinterpret_cast<const uint2*>(base + (size_t)i2 * 128);
        uint2 q3 = *reinterpret_cast<const uint2*>(base + (size_t)i3 * 128);
        uint2 q4 = *reinterpret_cast<const uint2*>(base + (size_t)i4 * 128);
        uint2 q5 = *reinterpret_cast<const uint2*>(base + (size_t)i5 * 128);
        uint2 q6 = *reinterpret_cast<const uint2*>(base + (size_t)i6 * 128);
        uint2 q7 = *reinterpret_cast<const uint2*>(base + (size_t)i7 * 128);
        ACC4(q0) ACC4(q1) ACC4(q2) ACC4(q3) ACC4(q4) ACC4(q5) ACC4(q6) ACC4(q7)
    }
    if (e < s1){
        int last = s1 - 1;
        int i0=csr[e];
        int i1=csr[min(e+1,last)],i2=csr[min(e+2,last)],i3=csr[min(e+3,last)];
        int i4=csr[min(e+4,last)],i5=csr[min(e+5,last)],i6=csr[min(e+6,last)],i7=csr[min(e+7,last)];
        uint2 z2_ = make_uint2(0,0);
        uint2 q0 = *reinterpret_cast<const uint2*>(base + (size_t)i0 * 128);
        uint2 q1 = *reinterpret_cast<const uint2*>(base + (size_t)i1 * 128);
        uint2 q2 = *reinterpret_cast<const uint2*>(base + (size_t)i2 * 128);
        uint2 q3 = *reinterpret_cast<const uint2*>(base + (size_t)i3 * 128);
        uint2 q4 = *reinterpret_cast<const uint2*>(base + (size_t)i4 * 128);
        uint2 q5 = *reinterpret_cast<const uint2*>(base + (size_t)i5 * 128);
        uint2 q6 = *reinterpret_cast<const uint2*>(base + (size_t)i6 * 128);
        uint2 q7 = *reinterpret_cast<const uint2*>(base + (size_t)i7 * 128);
        if (e+1 > last) q1 = z2_;
        if (e+2 > last) q2 = z2_;
        if (e+3 > last) q3 = z2_;
        if (e+4 > last) q4 = z2_;
        if (e+5 > last) q5 = z2_;
        if (e+6 > last) q6 = z2_;
        if (e+7 > last) q7 = z2_;
        ACC4(q0) ACC4(q1) ACC4(q2) ACC4(q3) ACC4(q4) ACC4(q5) ACC4(q6) ACC4(q7)
    }
    int d = s1 - s0;
    float inv = (d > 0) ? 1.0f / (float)d : 0.0f;
    uint2 zq = *reinterpret_cast<const uint2*>(ylz + (size_t)v * 128 + 64 + li * 4);
    float4 o;
    o.x = acc[0]*inv + bf16lo(zq.x);
    o.y = acc[1]*inv + bf16hi(zq.x);
    o.z = acc[2]*inv + bf16lo(zq.y);
    o.w = acc[3]*inv + bf16hi(zq.y);
    *reinterpret_cast<float4*>(out + (size_t)v * 64 + li * 4) = o;
}

extern "C" void kernel_launch(void* const* d_in, const int* in_sizes, int n_in,
                              void* d_out, int out_size, void* d_ws, size_t ws_size,
                              hipStream_t stream)
{
    const float* x   = (const float*)d_in[0];
    const int*   ei  = (const int*)d_in[1];
    const float* Wl0 = (const float*)d_in[2];
    const float* Wr0 = (const float*)d_in[3];
    const float* b0  = (const float*)d_in[4];
    const float* Wl1 = (const float*)d_in[5];
    const float* Wr1 = (const float*)d_in[6];
    const float* b1  = (const float*)d_in[7];
    const float* Wl2 = (const float*)d_in[8];
    const float* Wr2 = (const float*)d_in[9];
    const float* b2  = (const float*)d_in[10];

    int N = in_sizes[0] / D;
    int E = in_sizes[1] / 2;
    const int* src = ei;
    const int* dst = ei + E;
    int NBK = (N + BKN - 1) >> BSH;      // 391 for N=100000

    char* ws = (char*)d_ws;
    size_t off = 0;
    auto alloc = [&](size_t bytes) -> void* {
        void* p = ws + off;
        off = (off + bytes + 255) & ~(size_t)255;
        return p;
    };
    int*      bfill  = (int*)alloc((size_t)NBK * 4);
    int*      roff   = (int*)alloc((size_t)N * 4);
    int*      rend   = (int*)alloc((size_t)N * 4);
    int*      csr    = (int*)alloc((size_t)NBK * CAPB * 4);
    unsigned short* ylz = (unsigned short*)alloc((size_t)N * 256 * 2);   // also overlays binbuf
    unsigned short* h0  = (unsigned short*)alloc((size_t)N * D * 2);
    unsigned short* h1  = (unsigned short*)alloc((size_t)N * D * 2);
    unsigned short* WT0 = (unsigned short*)alloc((size_t)256 * 128 * 2);
    unsigned short* WT1 = (unsigned short*)alloc((size_t)256 * 128 * 2);
    unsigned short* WT2 = (unsigned short*)alloc((size_t)128 * 128 * 2);
    uint32_t* binbuf = (uint32_t*)ylz;   // binbuf (8.4 MB) dead before first ylz write

    hipMemsetAsync(bfill, 0, (size_t)NBK * 4, stream);

    bin_edges<<<(E + TILE - 1) / TILE, 256, 0, stream>>>(src, dst, bfill, binbuf, E, NBK);
    fill_bucket<<<NBK, 256, 0, stream>>>(binbuf, bfill, roff, rend, csr, N, NBK);

    wt_prep<<<(256 * 128 + 255) / 256, 256, 0, stream>>>(Wl0, Wr0, WT0, 128);
    wt_prep<<<(256 * 128 + 255) / 256, 256, 0, stream>>>(Wl1, Wr1, WT1, 128);
    wt_prep<<<(128 * 128 + 255) / 256, 256, 0, stream>>>(Wl2, Wr2, WT2, 64);

    int gG = (N + 127) / 128;
    int gA = (N + 15) / 16;

    // layer 0: ylz = x @ [Wl0|Wr0] + [0|b0]  (fp32 A, converted during staging)
    dense_gemm<256, true ><<<dim3(gG, 2), 256, 0, stream>>>(nullptr, x, WT0, b0, ylz, N);
    agg_relu<<<gA, 256, 0, stream>>>(ylz, roff, rend, csr, h0, N);
    // layer 1
    dense_gemm<256, false><<<dim3(gG, 2), 256, 0, stream>>>(h0, nullptr, WT1, b1, ylz, N);
    agg_relu<<<gA, 256, 0, stream>>>(ylz, roff, rend, csr, h1, N);
    // layer 2 (64-wide): out = mean_gather(yl2) + z2
    dense_gemm<128, false><<<dim3(gG, 1), 256, 0, stream>>>(h1, nullptr, WT2, b2, ylz, N);
    agg_out64<<<gA, 256, 0, stream>>>(ylz, roff, rend, csr, (float*)d_out, N);
}

// Round 13
// 275.862 us; speedup vs baseline: 1.1565x; 1.1565x over previous
//
#include <hip/hip_runtime.h>
#include <hip/hip_bf16.h>
#include <stdint.h>

#define D 128
#define BSH 8                 // bucket = 256 nodes
#define BKN 256               // nodes per bucket
#define TILE 4096             // edges per bin_edges block
#define CAPB 5376             // per-bucket slot capacity (mean ~4096, sd ~64, 20-sigma headroom)

typedef __attribute__((ext_vector_type(8))) short short8;
typedef __attribute__((ext_vector_type(4))) float f32x4;

typedef __attribute__((address_space(1))) const void gvoid;
typedef __attribute__((address_space(3))) void lvoid;

__device__ inline float bf16lo(uint32_t u){ return __uint_as_float(u << 16); }
__device__ inline float bf16hi(uint32_t u){ return __uint_as_float(u & 0xffff0000u); }
__device__ inline unsigned short f2bf(float f){
    union { __hip_bfloat16 h; unsigned short u; } cvt;
    cvt.h = __float2bfloat16(f);
    return cvt.u;
}

#define ACC8(q) \
    acc[0] += bf16lo(q.x); acc[1] += bf16hi(q.x); \
    acc[2] += bf16lo(q.y); acc[3] += bf16hi(q.y); \
    acc[4] += bf16lo(q.z); acc[5] += bf16hi(q.z); \
    acc[6] += bf16lo(q.w); acc[7] += bf16hi(q.w);

// ---------- binned edge scatter: direct 2-pass, padded per-bucket regions ----------
__global__ __launch_bounds__(256) void bin_edges(
    const int* __restrict__ src, const int* __restrict__ dst,
    int* __restrict__ bfill, uint32_t* __restrict__ binbuf, int E, int nbk)
{
    __shared__ int hist[400];
    __shared__ int cur[400];
    int t = threadIdx.x;
    int tile0 = blockIdx.x * TILE;
    int cnt = min(TILE, E - tile0);

    for (int i = t; i < nbk; i += 256) hist[i] = 0;
    __syncthreads();
    for (int i = t; i < cnt; i += 256)
        atomicAdd(&hist[dst[tile0 + i] >> BSH], 1);
    __syncthreads();
    for (int i = t; i < nbk; i += 256){
        int h = hist[i];
        int base = h ? atomicAdd(&bfill[i], h) : 0;
        cur[i] = i * CAPB + base;
    }
    __syncthreads();
    for (int i = t; i < cnt; i += 256){
        int d = dst[tile0 + i];
        int b = d >> BSH;
        int p = atomicAdd(&cur[b], 1);
        binbuf[p] = (uint32_t)src[tile0 + i] | ((uint32_t)(d & (BKN - 1)) << 17);
    }
}

// one block per 256-node bucket: histogram -> scan -> roff/rend + local csr scatter
// (round-11 version: no sort — per-node sorted order was measured null for agg FETCH)
__global__ __launch_bounds__(256) void fill_bucket(
    const uint32_t* __restrict__ binbuf, const int* __restrict__ bcnt,
    int* __restrict__ roff, int* __restrict__ rend, int* __restrict__ csr, int n, int nbk)
{
    __shared__ int hist[BKN];
    __shared__ int hist2[BKN];
    __shared__ int hb[BKN];
    __shared__ int sc[256];
    int b = blockIdx.x, t = threadIdx.x;
    int e0 = b * CAPB;
    int e1 = e0 + bcnt[b];
    int v0 = b << BSH;
    int nv = min(BKN, n - v0);

    hist[t] = 0; hist2[t] = 0;
    __syncthreads();
    for (int e = e0 + t; e < e1; e += 256)
        atomicAdd(&hist[binbuf[e] >> 17], 1);
    __syncthreads();
    int own = hist[t];
    sc[t] = own;
    __syncthreads();
    for (int o = 1; o < 256; o <<= 1){
        int x = (t >= o) ? sc[t - o] : 0;
        __syncthreads();
        sc[t] += x;
        __syncthreads();
    }
    int ex = sc[t] - own;
    hb[t] = ex;
    if (t < nv){
        roff[v0 + t] = e0 + ex;
        rend[v0 + t] = e0 + ex + own;
    }
    __syncthreads();
    for (int e = e0 + t; e < e1; e += 256){
        uint32_t p = binbuf[e];
        int local = p >> 17;
        int pos = e0 + hb[local] + atomicAdd(&hist2[local], 1);
        csr[pos] = (int)(p & 0x1FFFFu);
    }
}

// ---------- merged weight pre-transpose for all 3 layers ----------
// WT[j][k] = bf16(Wcat[k][j]), Wcat = [Wl | Wr]
__global__ void wt_prep_all(
    const float* __restrict__ Wl0, const float* __restrict__ Wr0,
    const float* __restrict__ Wl1, const float* __restrict__ Wr1,
    const float* __restrict__ Wl2, const float* __restrict__ Wr2,
    unsigned short* __restrict__ WT0, unsigned short* __restrict__ WT1,
    unsigned short* __restrict__ WT2)
{
    int idx = blockIdx.x * 256 + threadIdx.x;
    if (idx < 32768){
        int k = idx & 127, j = idx >> 7;
        WT0[j * 128 + k] = f2bf(j < 128 ? Wl0[k * 128 + j] : Wr0[k * 128 + (j - 128)]);
    } else if (idx < 65536){
        int i = idx - 32768; int k = i & 127, j = i >> 7;
        WT1[j * 128 + k] = f2bf(j < 128 ? Wl1[k * 128 + j] : Wr1[k * 128 + (j - 128)]);
    } else if (idx < 81920){
        int i = idx - 65536; int k = i & 127, j = i >> 7;
        WT2[j * 128 + k] = f2bf(j < 64 ? Wl2[k * 64 + j] : Wr2[k * 64 + (j - 64)]);
    }
}

// ---------- dense GEMM: ylz = X @ [Wl|Wr] + [0|b]  (M=n, N=NC, K=128) ----------
template<int NC, bool AF32>
__global__ __launch_bounds__(256, 3) void dense_gemm(
    const unsigned short* __restrict__ xb, const float* __restrict__ xf,
    const unsigned short* __restrict__ WT, const float* __restrict__ bias,
    unsigned short* __restrict__ ylz, int n)
{
    constexpr int DOUT = NC / 2;
    __shared__ __align__(16) char As[128 * 256];
    int tid = threadIdx.x, lane = tid & 63, wave = tid >> 6;
    int rbase = blockIdx.x * 128;
    int lrow = lane & 15, lk = (lane >> 4) * 8;
    int colbase = blockIdx.y * 128 + wave * 32;

    short8 bfr[4][2];
    #pragma unroll
    for (int kk = 0; kk < 4; kk++)
        #pragma unroll
        for (int cf = 0; cf < 2; cf++)
            bfr[kk][cf] = *reinterpret_cast<const short8*>(
                WT + (size_t)(colbase + cf * 16 + lrow) * 128 + kk * 32 + lk);

    if constexpr (AF32){
        int cb = (tid & 15) * 16;
        #pragma unroll
        for (int i = 0; i < 8; i++){
            int row = i * 16 + (tid >> 4);
            int grow = min(rbase + row, n - 1);
            const float* p = xf + (size_t)grow * 128 + (cb >> 1);
            float4 f0 = *reinterpret_cast<const float4*>(p);
            float4 f1 = *reinterpret_cast<const float4*>(p + 4);
            uint4 q;
            q.x = (uint32_t)f2bf(f0.x) | ((uint32_t)f2bf(f0.y) << 16);
            q.y = (uint32_t)f2bf(f0.z) | ((uint32_t)f2bf(f0.w) << 16);
            q.z = (uint32_t)f2bf(f1.x) | ((uint32_t)f2bf(f1.y) << 16);
            q.w = (uint32_t)f2bf(f1.z) | ((uint32_t)f2bf(f1.w) << 16);
            *reinterpret_cast<uint4*>(As + row * 256 + (cb ^ ((row & 7) << 4))) = q;
        }
    } else {
        int cb = (lane & 15) * 16;
        #pragma unroll
        for (int i = 0; i < 8; i++){
            int row = i * 16 + (tid >> 4);
            int grow = min(rbase + row, n - 1);
            const unsigned short* gsrc = xb + (size_t)grow * 128 + ((cb ^ ((row & 7) << 4)) >> 1);
            __builtin_amdgcn_global_load_lds(
                (gvoid*)gsrc,
                (lvoid*)(As + (i * 16 + wave * 4) * 256),
                16, 0, 0);
        }
    }
    __syncthreads();

    f32x4 acc[8][2];
    #pragma unroll
    for (int fr = 0; fr < 8; fr++)
        #pragma unroll
        for (int cf = 0; cf < 2; cf++)
            acc[fr][cf] = (f32x4){0.f, 0.f, 0.f, 0.f};

    #pragma unroll
    for (int kk = 0; kk < 4; kk++){
        int cb = kk * 64 + (lane >> 4) * 16;
        #pragma unroll
        for (int fr = 0; fr < 8; fr++){
            int row = fr * 16 + lrow;
            short8 a = *reinterpret_cast<const short8*>(As + row * 256 + (cb ^ ((row & 7) << 4)));
            #pragma unroll
            for (int cf = 0; cf < 2; cf++)
                acc[fr][cf] = __builtin_amdgcn_mfma_f32_16x16x32_bf16(bfr[kk][cf], a, acc[fr][cf], 0, 0, 0);
        }
    }

    float4 bv[2];
    #pragma unroll
    for (int cf = 0; cf < 2; cf++){
        int cg = colbase + cf * 16 + (lane >> 4) * 4;
        bv[cf] = (cg >= DOUT) ? *reinterpret_cast<const float4*>(bias + (cg - DOUT))
                              : (float4){0.f, 0.f, 0.f, 0.f};
    }

    #pragma unroll
    for (int fr = 0; fr < 8; fr++){
        int row = rbase + fr * 16 + lrow;
        if (row < n){
            #pragma unroll
            for (int cf = 0; cf < 2; cf++){
                int cg = colbase + cf * 16 + (lane >> 4) * 4;
                uint2 o;
                o.x = (uint32_t)f2bf(acc[fr][cf][0] + bv[cf].x) |
                      ((uint32_t)f2bf(acc[fr][cf][1] + bv[cf].y) << 16);
                o.y = (uint32_t)f2bf(acc[fr][cf][2] + bv[cf].z) |
                      ((uint32_t)f2bf(acc[fr][cf][3] + bv[cf].w) << 16);
                *reinterpret_cast<uint2*>(ylz + (size_t)row * NC + cg) = o;
            }
        }
    }
}

// ---------- aggregation: h = relu(mean_gather(yl) + z), yl/z in ylz[N][256] ----------
__global__ __launch_bounds__(256, 4) void agg_relu(
    const unsigned short* __restrict__ ylz, const int* __restrict__ roff,
    const int* __restrict__ rend,
    const int* __restrict__ csr, unsigned short* __restrict__ hout, int n)
{
    int grp = threadIdx.x >> 4, li = threadIdx.x & 15;
    int v = blockIdx.x * 16 + grp;
    if (v >= n) return;
    int s0 = roff[v], s1 = rend[v];
    const unsigned short* base = ylz + li * 8;
    float acc[8] = {0.f,0.f,0.f,0.f,0.f,0.f,0.f,0.f};
    int e = s0;
    for (; e + 8 <= s1; e += 8){
        int i0=csr[e],i1=csr[e+1],i2=csr[e+2],i3=csr[e+3];
        int i4=csr[e+4],i5=csr[e+5],i6=csr[e+6],i7=csr[e+7];
        uint4 q0 = *reinterpret_cast<const uint4*>(base + (size_t)i0 * 256);
        uint4 q1 = *reinterpret_cast<const uint4*>(base + (size_t)i1 * 256);
        uint4 q2 = *reinterpret_cast<const uint4*>(base + (size_t)i2 * 256);
        uint4 q3 = *reinterpret_cast<const uint4*>(base + (size_t)i3 * 256);
        uint4 q4 = *reinterpret_cast<const uint4*>(base + (size_t)i4 * 256);
        uint4 q5 = *reinterpret_cast<const uint4*>(base + (size_t)i5 * 256);
        uint4 q6 = *reinterpret_cast<const uint4*>(base + (size_t)i6 * 256);
        uint4 q7 = *reinterpret_cast<const uint4*>(base + (size_t)i7 * 256);
        ACC8(q0) ACC8(q1) ACC8(q2) ACC8(q3) ACC8(q4) ACC8(q5) ACC8(q6) ACC8(q7)
    }
    if (e < s1){
        int last = s1 - 1;
        int i0=csr[e];
        int i1=csr[min(e+1,last)],i2=csr[min(e+2,last)],i3=csr[min(e+3,last)];
        int i4=csr[min(e+4,last)],i5=csr[min(e+5,last)],i6=csr[min(e+6,last)],i7=csr[min(e+7,last)];
        uint4 z4 = make_uint4(0,0,0,0);
        uint4 q0 = *reinterpret_cast<const uint4*>(base + (size_t)i0 * 256);
        uint4 q1 = *reinterpret_cast<const uint4*>(base + (size_t)i1 * 256);
        uint4 q2 = *reinterpret_cast<const uint4*>(base + (size_t)i2 * 256);
        uint4 q3 = *reinterpret_cast<const uint4*>(base + (size_t)i3 * 256);
        uint4 q4 = *reinterpret_cast<const uint4*>(base + (size_t)i4 * 256);
        uint4 q5 = *reinterpret_cast<const uint4*>(base + (size_t)i5 * 256);
        uint4 q6 = *reinterpret_cast<const uint4*>(base + (size_t)i6 * 256);
        uint4 q7 = *reinterpret_cast<const uint4*>(base + (size_t)i7 * 256);
        if (e+1 > last) q1 = z4;
        if (e+2 > last) q2 = z4;
        if (e+3 > last) q3 = z4;
        if (e+4 > last) q4 = z4;
        if (e+5 > last) q5 = z4;
        if (e+6 > last) q6 = z4;
        if (e+7 > last) q7 = z4;
        ACC8(q0) ACC8(q1) ACC8(q2) ACC8(q3) ACC8(q4) ACC8(q5) ACC8(q6) ACC8(q7)
    }
    int d = s1 - s0;
    float inv = (d > 0) ? 1.0f / (float)d : 0.0f;
    uint4 zq = *reinterpret_cast<const uint4*>(ylz + (size_t)v * 256 + 128 + li * 8);
    float z0=bf16lo(zq.x), z1=bf16hi(zq.x), z2=bf16lo(zq.y), z3=bf16hi(zq.y);
    float z4_=bf16lo(zq.z), z5=bf16hi(zq.z), z6=bf16lo(zq.w), z7=bf16hi(zq.w);
    uint4 o;
    o.x = (uint32_t)f2bf(fmaxf(acc[0]*inv+z0,0.f)) | ((uint32_t)f2bf(fmaxf(acc[1]*inv+z1,0.f)) << 16);
    o.y = (uint32_t)f2bf(fmaxf(acc[2]*inv+z2,0.f)) | ((uint32_t)f2bf(fmaxf(acc[3]*inv+z3,0.f)) << 16);
    o.z = (uint32_t)f2bf(fmaxf(acc[4]*inv+z4_,0.f)) | ((uint32_t)f2bf(fmaxf(acc[5]*inv+z5,0.f)) << 16);
    o.w = (uint32_t)f2bf(fmaxf(acc[6]*inv+z6,0.f)) | ((uint32_t)f2bf(fmaxf(acc[7]*inv+z7,0.f)) << 16);
    *reinterpret_cast<uint4*>(hout + (size_t)v * 128 + li * 8) = o;
}

// ---------- final layer aggregation: out = mean_gather(yl2) + z2, fp32 out, ylz[N][128] ----------
// 8 lanes per node (16 B uint4 gathers on 128 B rows), 32 nodes per block.
__global__ __launch_bounds__(256, 4) void agg_out64(
    const unsigned short* __restrict__ ylz, const int* __restrict__ roff,
    const int* __restrict__ rend,
    const int* __restrict__ csr, float* __restrict__ out, int n)
{
    int grp = threadIdx.x >> 3, li = threadIdx.x & 7;
    int v = blockIdx.x * 32 + grp;
    if (v >= n) return;
    int s0 = roff[v], s1 = rend[v];
    const unsigned short* base = ylz + li * 8;
    float acc[8] = {0.f,0.f,0.f,0.f,0.f,0.f,0.f,0.f};
    int e = s0;
    for (; e + 8 <= s1; e += 8){
        int i0=csr[e],i1=csr[e+1],i2=csr[e+2],i3=csr[e+3];
        int i4=csr[e+4],i5=csr[e+5],i6=csr[e+6],i7=csr[e+7];
        uint4 q0 = *reinterpret_cast<const uint4*>(base + (size_t)i0 * 128);
        uint4 q1 = *reinterpret_cast<const uint4*>(base + (size_t)i1 * 128);
        uint4 q2 = *reinterpret_cast<const uint4*>(base + (size_t)i2 * 128);
        uint4 q3 = *reinterpret_cast<const uint4*>(base + (size_t)i3 * 128);
        uint4 q4 = *reinterpret_cast<const uint4*>(base + (size_t)i4 * 128);
        uint4 q5 = *reinterpret_cast<const uint4*>(base + (size_t)i5 * 128);
        uint4 q6 = *reinterpret_cast<const uint4*>(base + (size_t)i6 * 128);
        uint4 q7 = *reinterpret_cast<const uint4*>(base + (size_t)i7 * 128);
        ACC8(q0) ACC8(q1) ACC8(q2) ACC8(q3) ACC8(q4) ACC8(q5) ACC8(q6) ACC8(q7)
    }
    if (e < s1){
        int last = s1 - 1;
        int i0=csr[e];
        int i1=csr[min(e+1,last)],i2=csr[min(e+2,last)],i3=csr[min(e+3,last)];
        int i4=csr[min(e+4,last)],i5=csr[min(e+5,last)],i6=csr[min(e+6,last)],i7=csr[min(e+7,last)];
        uint4 z4 = make_uint4(0,0,0,0);
        uint4 q0 = *reinterpret_cast<const uint4*>(base + (size_t)i0 * 128);
        uint4 q1 = *reinterpret_cast<const uint4*>(base + (size_t)i1 * 128);
        uint4 q2 = *reinterpret_cast<const uint4*>(base + (size_t)i2 * 128);
        uint4 q3 = *reinterpret_cast<const uint4*>(base + (size_t)i3 * 128);
        uint4 q4 = *reinterpret_cast<const uint4*>(base + (size_t)i4 * 128);
        uint4 q5 = *reinterpret_cast<const uint4*>(base + (size_t)i5 * 128);
        uint4 q6 = *reinterpret_cast<const uint4*>(base + (size_t)i6 * 128);
        uint4 q7 = *reinterpret_cast<const uint4*>(base + (size_t)i7 * 128);
        if (e+1 > last) q1 = z4;
        if (e+2 > last) q2 = z4;
        if (e+3 > last) q3 = z4;
        if (e+4 > last) q4 = z4;
        if (e+5 > last) q5 = z4;
        if (e+6 > last) q6 = z4;
        if (e+7 > last) q7 = z4;
        ACC8(q0) ACC8(q1) ACC8(q2) ACC8(q3) ACC8(q4) ACC8(q5) ACC8(q6) ACC8(q7)
    }
    int d = s1 - s0;
    float inv = (d > 0) ? 1.0f / (float)d : 0.0f;
    uint4 zq = *reinterpret_cast<const uint4*>(ylz + (size_t)v * 128 + 64 + li * 8);
    float4 o0, o1;
    o0.x = acc[0]*inv + bf16lo(zq.x);
    o0.y = acc[1]*inv + bf16hi(zq.x);
    o0.z = acc[2]*inv + bf16lo(zq.y);
    o0.w = acc[3]*inv + bf16hi(zq.y);
    o1.x = acc[4]*inv + bf16lo(zq.z);
    o1.y = acc[5]*inv + bf16hi(zq.z);
    o1.z = acc[6]*inv + bf16lo(zq.w);
    o1.w = acc[7]*inv + bf16hi(zq.w);
    *reinterpret_cast<float4*>(out + (size_t)v * 64 + li * 8) = o0;
    *reinterpret_cast<float4*>(out + (size_t)v * 64 + li * 8 + 4) = o1;
}

extern "C" void kernel_launch(void* const* d_in, const int* in_sizes, int n_in,
                              void* d_out, int out_size, void* d_ws, size_t ws_size,
                              hipStream_t stream)
{
    const float* x   = (const float*)d_in[0];
    const int*   ei  = (const int*)d_in[1];
    const float* Wl0 = (const float*)d_in[2];
    const float* Wr0 = (const float*)d_in[3];
    const float* b0  = (const float*)d_in[4];
    const float* Wl1 = (const float*)d_in[5];
    const float* Wr1 = (const float*)d_in[6];
    const float* b1  = (const float*)d_in[7];
    const float* Wl2 = (const float*)d_in[8];
    const float* Wr2 = (const float*)d_in[9];
    const float* b2  = (const float*)d_in[10];

    int N = in_sizes[0] / D;
    int E = in_sizes[1] / 2;
    const int* src = ei;
    const int* dst = ei + E;
    int NBK = (N + BKN - 1) >> BSH;      // 391 for N=100000

    char* ws = (char*)d_ws;
    size_t off = 0;
    auto alloc = [&](size_t bytes) -> void* {
        void* p = ws + off;
        off = (off + bytes + 255) & ~(size_t)255;
        return p;
    };
    int*      bfill  = (int*)alloc((size_t)NBK * 4);
    int*      roff   = (int*)alloc((size_t)N * 4);
    int*      rend   = (int*)alloc((size_t)N * 4);
    int*      csr    = (int*)alloc((size_t)NBK * CAPB * 4);
    unsigned short* ylz = (unsigned short*)alloc((size_t)N * 256 * 2);   // also overlays binbuf
    unsigned short* h0  = (unsigned short*)alloc((size_t)N * D * 2);
    unsigned short* h1  = (unsigned short*)alloc((size_t)N * D * 2);
    unsigned short* WT0 = (unsigned short*)alloc((size_t)256 * 128 * 2);
    unsigned short* WT1 = (unsigned short*)alloc((size_t)256 * 128 * 2);
    unsigned short* WT2 = (unsigned short*)alloc((size_t)128 * 128 * 2);
    uint32_t* binbuf = (uint32_t*)ylz;   // binbuf (8.4 MB) dead before first ylz write

    hipMemsetAsync(bfill, 0, (size_t)NBK * 4, stream);

    bin_edges<<<(E + TILE - 1) / TILE, 256, 0, stream>>>(src, dst, bfill, binbuf, E, NBK);
    fill_bucket<<<NBK, 256, 0, stream>>>(binbuf, bfill, roff, rend, csr, N, NBK);

    wt_prep_all<<<320, 256, 0, stream>>>(Wl0, Wr0, Wl1, Wr1, Wl2, Wr2, WT0, WT1, WT2);

    int gG = (N + 127) / 128;
    int gA = (N + 15) / 16;
    int gA2 = (N + 31) / 32;

    // layer 0: ylz = x @ [Wl0|Wr0] + [0|b0]  (fp32 A, converted during staging)
    dense_gemm<256, true ><<<dim3(gG, 2), 256, 0, stream>>>(nullptr, x, WT0, b0, ylz, N);
    agg_relu<<<gA, 256, 0, stream>>>(ylz, roff, rend, csr, h0, N);
    // layer 1
    dense_gemm<256, false><<<dim3(gG, 2), 256, 0, stream>>>(h0, nullptr, WT1, b1, ylz, N);
    agg_relu<<<gA, 256, 0, stream>>>(ylz, roff, rend, csr, h1, N);
    // layer 2 (64-wide): out = mean_gather(yl2) + z2
    dense_gemm<128, false><<<dim3(gG, 1), 256, 0, stream>>>(h1, nullptr, WT2, b2, ylz, N);
    agg_out64<<<gA2, 256, 0, stream>>>(ylz, roff, rend, csr, (float*)d_out, N);
}

// Round 14
// 262.583 us; speedup vs baseline: 1.2150x; 1.0506x over previous
//
#include <hip/hip_runtime.h>
#include <hip/hip_bf16.h>
#include <stdint.h>

#define D 128
#define BSH 8                 // bucket = 256 nodes
#define BKN 256               // nodes per bucket
#define TILE 4096             // edges per bin_edges block
#define CAPB 5376             // per-bucket slot capacity (mean ~4096, sd ~64, 20-sigma headroom)

typedef __attribute__((ext_vector_type(8))) short short8;
typedef __attribute__((ext_vector_type(4))) float f32x4;

typedef __attribute__((address_space(1))) const void gvoid;
typedef __attribute__((address_space(3))) void lvoid;

__device__ inline float bf16lo(uint32_t u){ return __uint_as_float(u << 16); }
__device__ inline float bf16hi(uint32_t u){ return __uint_as_float(u & 0xffff0000u); }
__device__ inline unsigned short f2bf(float f){
    union { __hip_bfloat16 h; unsigned short u; } cvt;
    cvt.h = __float2bfloat16(f);
    return cvt.u;
}

#define ACC8(q) \
    acc[0] += bf16lo(q.x); acc[1] += bf16hi(q.x); \
    acc[2] += bf16lo(q.y); acc[3] += bf16hi(q.y); \
    acc[4] += bf16lo(q.z); acc[5] += bf16hi(q.z); \
    acc[6] += bf16lo(q.w); acc[7] += bf16hi(q.w);

// ---------- K0: bin_edges (blocks [0, nBin)) ∥ wt_prep_all (blocks [nBin, ...)) ----------
__global__ __launch_bounds__(256) void prep_and_bin(
    const int* __restrict__ src, const int* __restrict__ dst,
    int* __restrict__ bfill, uint32_t* __restrict__ binbuf, int E, int nbk, int nBin,
    const float* __restrict__ Wl0, const float* __restrict__ Wr0,
    const float* __restrict__ Wl1, const float* __restrict__ Wr1,
    const float* __restrict__ Wl2, const float* __restrict__ Wr2,
    unsigned short* __restrict__ WT0, unsigned short* __restrict__ WT1,
    unsigned short* __restrict__ WT2)
{
    __shared__ int hist[400];
    __shared__ int cur[400];
    int t = threadIdx.x;
    if ((int)blockIdx.x < nBin){
        int tile0 = blockIdx.x * TILE;
        int cnt = min(TILE, E - tile0);
        for (int i = t; i < nbk; i += 256) hist[i] = 0;
        __syncthreads();
        for (int i = t; i < cnt; i += 256)
            atomicAdd(&hist[dst[tile0 + i] >> BSH], 1);
        __syncthreads();
        for (int i = t; i < nbk; i += 256){
            int h = hist[i];
            int base = h ? atomicAdd(&bfill[i], h) : 0;
            cur[i] = i * CAPB + base;
        }
        __syncthreads();
        for (int i = t; i < cnt; i += 256){
            int d = dst[tile0 + i];
            int b = d >> BSH;
            int p = atomicAdd(&cur[b], 1);
            binbuf[p] = (uint32_t)src[tile0 + i] | ((uint32_t)(d & (BKN - 1)) << 17);
        }
    } else {
        int idx = ((int)blockIdx.x - nBin) * 256 + t;
        if (idx < 32768){
            int k = idx & 127, j = idx >> 7;
            WT0[j * 128 + k] = f2bf(j < 128 ? Wl0[k * 128 + j] : Wr0[k * 128 + (j - 128)]);
        } else if (idx < 65536){
            int i = idx - 32768; int k = i & 127, j = i >> 7;
            WT1[j * 128 + k] = f2bf(j < 128 ? Wl1[k * 128 + j] : Wr1[k * 128 + (j - 128)]);
        } else if (idx < 81920){
            int i = idx - 65536; int k = i & 127, j = i >> 7;
            WT2[j * 128 + k] = f2bf(j < 64 ? Wl2[k * 64 + j] : Wr2[k * 64 + (j - 64)]);
        }
    }
}

// ---------- K1: fill_bucket (blocks [0, nbk)) ∥ layer-0 GEMM (blocks [nbk, nbk+2*gG)) ----------
// gemm part: ylz = x(fp32) @ [Wl0|Wr0] + [0|b0], BM=128, NC=256, convert-during-staging,
// XOR-swizzled LDS (byte ^= (row&7)<<4), swapped-operand MFMA, uint2 packed stores.
__global__ __launch_bounds__(256, 3) void gemm0_fill(
    const float* __restrict__ xf, const unsigned short* __restrict__ WT,
    const float* __restrict__ bias, unsigned short* __restrict__ ylz, int n,
    const uint32_t* __restrict__ binbuf, const int* __restrict__ bcnt,
    int* __restrict__ roff, int* __restrict__ rend, int* __restrict__ csr,
    int nbk, int gG)
{
    __shared__ __align__(16) char smem[128 * 256];
    int tid = threadIdx.x;

    if ((int)blockIdx.x < nbk){
        // ---- fill_bucket body (4KB of smem) ----
        int* hist  = (int*)smem;
        int* hist2 = hist + 256;
        int* hb    = hist2 + 256;
        int* sc    = hb + 256;
        int b = blockIdx.x, t = tid;
        int e0 = b * CAPB;
        int e1 = e0 + bcnt[b];
        int v0 = b << BSH;
        int nv = min(BKN, n - v0);

        hist[t] = 0; hist2[t] = 0;
        __syncthreads();
        for (int e = e0 + t; e < e1; e += 256)
            atomicAdd(&hist[binbuf[e] >> 17], 1);
        __syncthreads();
        int own = hist[t];
        sc[t] = own;
        __syncthreads();
        for (int o = 1; o < 256; o <<= 1){
            int x = (t >= o) ? sc[t - o] : 0;
            __syncthreads();
            sc[t] += x;
            __syncthreads();
        }
        int ex = sc[t] - own;
        hb[t] = ex;
        if (t < nv){
            roff[v0 + t] = e0 + ex;
            rend[v0 + t] = e0 + ex + own;
        }
        __syncthreads();
        for (int e = e0 + t; e < e1; e += 256){
            uint32_t p = binbuf[e];
            int local = p >> 17;
            int pos = e0 + hb[local] + atomicAdd(&hist2[local], 1);
            csr[pos] = (int)(p & 0x1FFFFu);
        }
        return;
    }

    // ---- layer-0 GEMM body ----
    int bid = (int)blockIdx.x - nbk;
    int bx = bid % gG, by = bid / gG;
    char* As = smem;
    int lane = tid & 63, wave = tid >> 6;
    int rbase = bx * 128;
    int lrow = lane & 15, lk = (lane >> 4) * 8;
    int colbase = by * 128 + wave * 32;

    short8 bfr[4][2];
    #pragma unroll
    for (int kk = 0; kk < 4; kk++)
        #pragma unroll
        for (int cf = 0; cf < 2; cf++)
            bfr[kk][cf] = *reinterpret_cast<const short8*>(
                WT + (size_t)(colbase + cf * 16 + lrow) * 128 + kk * 32 + lk);

    {
        int cb = (tid & 15) * 16;
        #pragma unroll
        for (int i = 0; i < 8; i++){
            int row = i * 16 + (tid >> 4);
            int grow = min(rbase + row, n - 1);
            const float* p = xf + (size_t)grow * 128 + (cb >> 1);
            float4 f0 = *reinterpret_cast<const float4*>(p);
            float4 f1 = *reinterpret_cast<const float4*>(p + 4);
            uint4 q;
            q.x = (uint32_t)f2bf(f0.x) | ((uint32_t)f2bf(f0.y) << 16);
            q.y = (uint32_t)f2bf(f0.z) | ((uint32_t)f2bf(f0.w) << 16);
            q.z = (uint32_t)f2bf(f1.x) | ((uint32_t)f2bf(f1.y) << 16);
            q.w = (uint32_t)f2bf(f1.z) | ((uint32_t)f2bf(f1.w) << 16);
            *reinterpret_cast<uint4*>(As + row * 256 + (cb ^ ((row & 7) << 4))) = q;
        }
    }
    __syncthreads();

    f32x4 acc[8][2];
    #pragma unroll
    for (int fr = 0; fr < 8; fr++)
        #pragma unroll
        for (int cf = 0; cf < 2; cf++)
            acc[fr][cf] = (f32x4){0.f, 0.f, 0.f, 0.f};

    #pragma unroll
    for (int kk = 0; kk < 4; kk++){
        int cb = kk * 64 + (lane >> 4) * 16;
        #pragma unroll
        for (int fr = 0; fr < 8; fr++){
            int row = fr * 16 + lrow;
            short8 a = *reinterpret_cast<const short8*>(As + row * 256 + (cb ^ ((row & 7) << 4)));
            #pragma unroll
            for (int cf = 0; cf < 2; cf++)
                acc[fr][cf] = __builtin_amdgcn_mfma_f32_16x16x32_bf16(bfr[kk][cf], a, acc[fr][cf], 0, 0, 0);
        }
    }

    float4 bv[2];
    #pragma unroll
    for (int cf = 0; cf < 2; cf++){
        int cg = colbase + cf * 16 + (lane >> 4) * 4;
        bv[cf] = (cg >= 128) ? *reinterpret_cast<const float4*>(bias + (cg - 128))
                             : (float4){0.f, 0.f, 0.f, 0.f};
    }

    #pragma unroll
    for (int fr = 0; fr < 8; fr++){
        int row = rbase + fr * 16 + lrow;
        if (row < n){
            #pragma unroll
            for (int cf = 0; cf < 2; cf++){
                int cg = colbase + cf * 16 + (lane >> 4) * 4;
                uint2 o;
                o.x = (uint32_t)f2bf(acc[fr][cf][0] + bv[cf].x) |
                      ((uint32_t)f2bf(acc[fr][cf][1] + bv[cf].y) << 16);
                o.y = (uint32_t)f2bf(acc[fr][cf][2] + bv[cf].z) |
                      ((uint32_t)f2bf(acc[fr][cf][3] + bv[cf].w) << 16);
                *reinterpret_cast<uint2*>(ylz + (size_t)row * 256 + cg) = o;
            }
        }
    }
}

// ---------- dense GEMM (layers 1,2): ylz = X(bf16) @ [Wl|Wr] + [0|b] ----------
template<int NC>
__global__ __launch_bounds__(256, 3) void dense_gemm(
    const unsigned short* __restrict__ xb,
    const unsigned short* __restrict__ WT, const float* __restrict__ bias,
    unsigned short* __restrict__ ylz, int n)
{
    constexpr int DOUT = NC / 2;
    __shared__ __align__(16) char As[128 * 256];
    int tid = threadIdx.x, lane = tid & 63, wave = tid >> 6;
    int rbase = blockIdx.x * 128;
    int lrow = lane & 15, lk = (lane >> 4) * 8;
    int colbase = blockIdx.y * 128 + wave * 32;

    short8 bfr[4][2];
    #pragma unroll
    for (int kk = 0; kk < 4; kk++)
        #pragma unroll
        for (int cf = 0; cf < 2; cf++)
            bfr[kk][cf] = *reinterpret_cast<const short8*>(
                WT + (size_t)(colbase + cf * 16 + lrow) * 128 + kk * 32 + lk);

    {
        int cb = (lane & 15) * 16;
        #pragma unroll
        for (int i = 0; i < 8; i++){
            int row = i * 16 + (tid >> 4);
            int grow = min(rbase + row, n - 1);
            const unsigned short* gsrc = xb + (size_t)grow * 128 + ((cb ^ ((row & 7) << 4)) >> 1);
            __builtin_amdgcn_global_load_lds(
                (gvoid*)gsrc,
                (lvoid*)(As + (i * 16 + wave * 4) * 256),
                16, 0, 0);
        }
    }
    __syncthreads();

    f32x4 acc[8][2];
    #pragma unroll
    for (int fr = 0; fr < 8; fr++)
        #pragma unroll
        for (int cf = 0; cf < 2; cf++)
            acc[fr][cf] = (f32x4){0.f, 0.f, 0.f, 0.f};

    #pragma unroll
    for (int kk = 0; kk < 4; kk++){
        int cb = kk * 64 + (lane >> 4) * 16;
        #pragma unroll
        for (int fr = 0; fr < 8; fr++){
            int row = fr * 16 + lrow;
            short8 a = *reinterpret_cast<const short8*>(As + row * 256 + (cb ^ ((row & 7) << 4)));
            #pragma unroll
            for (int cf = 0; cf < 2; cf++)
                acc[fr][cf] = __builtin_amdgcn_mfma_f32_16x16x32_bf16(bfr[kk][cf], a, acc[fr][cf], 0, 0, 0);
        }
    }

    float4 bv[2];
    #pragma unroll
    for (int cf = 0; cf < 2; cf++){
        int cg = colbase + cf * 16 + (lane >> 4) * 4;
        bv[cf] = (cg >= DOUT) ? *reinterpret_cast<const float4*>(bias + (cg - DOUT))
                              : (float4){0.f, 0.f, 0.f, 0.f};
    }

    #pragma unroll
    for (int fr = 0; fr < 8; fr++){
        int row = rbase + fr * 16 + lrow;
        if (row < n){
            #pragma unroll
            for (int cf = 0; cf < 2; cf++){
                int cg = colbase + cf * 16 + (lane >> 4) * 4;
                uint2 o;
                o.x = (uint32_t)f2bf(acc[fr][cf][0] + bv[cf].x) |
                      ((uint32_t)f2bf(acc[fr][cf][1] + bv[cf].y) << 16);
                o.y = (uint32_t)f2bf(acc[fr][cf][2] + bv[cf].z) |
                      ((uint32_t)f2bf(acc[fr][cf][3] + bv[cf].w) << 16);
                *reinterpret_cast<uint2*>(ylz + (size_t)row * NC + cg) = o;
            }
        }
    }
}

// ---------- aggregation: h = relu(mean_gather(yl) + z), yl/z in ylz[N][256] ----------
__global__ __launch_bounds__(256, 4) void agg_relu(
    const unsigned short* __restrict__ ylz, const int* __restrict__ roff,
    const int* __restrict__ rend,
    const int* __restrict__ csr, unsigned short* __restrict__ hout, int n)
{
    int grp = threadIdx.x >> 4, li = threadIdx.x & 15;
    int v = blockIdx.x * 16 + grp;
    if (v >= n) return;
    int s0 = roff[v], s1 = rend[v];
    const unsigned short* base = ylz + li * 8;
    float acc[8] = {0.f,0.f,0.f,0.f,0.f,0.f,0.f,0.f};
    int e = s0;
    for (; e + 8 <= s1; e += 8){
        int i0=csr[e],i1=csr[e+1],i2=csr[e+2],i3=csr[e+3];
        int i4=csr[e+4],i5=csr[e+5],i6=csr[e+6],i7=csr[e+7];
        uint4 q0 = *reinterpret_cast<const uint4*>(base + (size_t)i0 * 256);
        uint4 q1 = *reinterpret_cast<const uint4*>(base + (size_t)i1 * 256);
        uint4 q2 = *reinterpret_cast<const uint4*>(base + (size_t)i2 * 256);
        uint4 q3 = *reinterpret_cast<const uint4*>(base + (size_t)i3 * 256);
        uint4 q4 = *reinterpret_cast<const uint4*>(base + (size_t)i4 * 256);
        uint4 q5 = *reinterpret_cast<const uint4*>(base + (size_t)i5 * 256);
        uint4 q6 = *reinterpret_cast<const uint4*>(base + (size_t)i6 * 256);
        uint4 q7 = *reinterpret_cast<const uint4*>(base + (size_t)i7 * 256);
        ACC8(q0) ACC8(q1) ACC8(q2) ACC8(q3) ACC8(q4) ACC8(q5) ACC8(q6) ACC8(q7)
    }
    if (e < s1){
        int last = s1 - 1;
        int i0=csr[e];
        int i1=csr[min(e+1,last)],i2=csr[min(e+2,last)],i3=csr[min(e+3,last)];
        int i4=csr[min(e+4,last)],i5=csr[min(e+5,last)],i6=csr[min(e+6,last)],i7=csr[min(e+7,last)];
        uint4 z4 = make_uint4(0,0,0,0);
        uint4 q0 = *reinterpret_cast<const uint4*>(base + (size_t)i0 * 256);
        uint4 q1 = *reinterpret_cast<const uint4*>(base + (size_t)i1 * 256);
        uint4 q2 = *reinterpret_cast<const uint4*>(base + (size_t)i2 * 256);
        uint4 q3 = *reinterpret_cast<const uint4*>(base + (size_t)i3 * 256);
        uint4 q4 = *reinterpret_cast<const uint4*>(base + (size_t)i4 * 256);
        uint4 q5 = *reinterpret_cast<const uint4*>(base + (size_t)i5 * 256);
        uint4 q6 = *reinterpret_cast<const uint4*>(base + (size_t)i6 * 256);
        uint4 q7 = *reinterpret_cast<const uint4*>(base + (size_t)i7 * 256);
        if (e+1 > last) q1 = z4;
        if (e+2 > last) q2 = z4;
        if (e+3 > last) q3 = z4;
        if (e+4 > last) q4 = z4;
        if (e+5 > last) q5 = z4;
        if (e+6 > last) q6 = z4;
        if (e+7 > last) q7 = z4;
        ACC8(q0) ACC8(q1) ACC8(q2) ACC8(q3) ACC8(q4) ACC8(q5) ACC8(q6) ACC8(q7)
    }
    int d = s1 - s0;
    float inv = (d > 0) ? 1.0f / (float)d : 0.0f;
    uint4 zq = *reinterpret_cast<const uint4*>(ylz + (size_t)v * 256 + 128 + li * 8);
    float z0=bf16lo(zq.x), z1=bf16hi(zq.x), z2=bf16lo(zq.y), z3=bf16hi(zq.y);
    float z4_=bf16lo(zq.z), z5=bf16hi(zq.z), z6=bf16lo(zq.w), z7=bf16hi(zq.w);
    uint4 o;
    o.x = (uint32_t)f2bf(fmaxf(acc[0]*inv+z0,0.f)) | ((uint32_t)f2bf(fmaxf(acc[1]*inv+z1,0.f)) << 16);
    o.y = (uint32_t)f2bf(fmaxf(acc[2]*inv+z2,0.f)) | ((uint32_t)f2bf(fmaxf(acc[3]*inv+z3,0.f)) << 16);
    o.z = (uint32_t)f2bf(fmaxf(acc[4]*inv+z4_,0.f)) | ((uint32_t)f2bf(fmaxf(acc[5]*inv+z5,0.f)) << 16);
    o.w = (uint32_t)f2bf(fmaxf(acc[6]*inv+z6,0.f)) | ((uint32_t)f2bf(fmaxf(acc[7]*inv+z7,0.f)) << 16);
    *reinterpret_cast<uint4*>(hout + (size_t)v * 128 + li * 8) = o;
}

// ---------- final layer aggregation: out = mean_gather(yl2) + z2, fp32 out, ylz[N][128] ----------
__global__ __launch_bounds__(256, 4) void agg_out64(
    const unsigned short* __restrict__ ylz, const int* __restrict__ roff,
    const int* __restrict__ rend,
    const int* __restrict__ csr, float* __restrict__ out, int n)
{
    int grp = threadIdx.x >> 3, li = threadIdx.x & 7;
    int v = blockIdx.x * 32 + grp;
    if (v >= n) return;
    int s0 = roff[v], s1 = rend[v];
    const unsigned short* base = ylz + li * 8;
    float acc[8] = {0.f,0.f,0.f,0.f,0.f,0.f,0.f,0.f};
    int e = s0;
    for (; e + 8 <= s1; e += 8){
        int i0=csr[e],i1=csr[e+1],i2=csr[e+2],i3=csr[e+3];
        int i4=csr[e+4],i5=csr[e+5],i6=csr[e+6],i7=csr[e+7];
        uint4 q0 = *reinterpret_cast<const uint4*>(base + (size_t)i0 * 128);
        uint4 q1 = *reinterpret_cast<const uint4*>(base + (size_t)i1 * 128);
        uint4 q2 = *reinterpret_cast<const uint4*>(base + (size_t)i2 * 128);
        uint4 q3 = *reinterpret_cast<const uint4*>(base + (size_t)i3 * 128);
        uint4 q4 = *reinterpret_cast<const uint4*>(base + (size_t)i4 * 128);
        uint4 q5 = *reinterpret_cast<const uint4*>(base + (size_t)i5 * 128);
        uint4 q6 = *reinterpret_cast<const uint4*>(base + (size_t)i6 * 128);
        uint4 q7 = *reinterpret_cast<const uint4*>(base + (size_t)i7 * 128);
        ACC8(q0) ACC8(q1) ACC8(q2) ACC8(q3) ACC8(q4) ACC8(q5) ACC8(q6) ACC8(q7)
    }
    if (e < s1){
        int last = s1 - 1;
        int i0=csr[e];
        int i1=csr[min(e+1,last)],i2=csr[min(e+2,last)],i3=csr[min(e+3,last)];
        int i4=csr[min(e+4,last)],i5=csr[min(e+5,last)],i6=csr[min(e+6,last)],i7=csr[min(e+7,last)];
        uint4 z4 = make_uint4(0,0,0,0);
        uint4 q0 = *reinterpret_cast<const uint4*>(base + (size_t)i0 * 128);
        uint4 q1 = *reinterpret_cast<const uint4*>(base + (size_t)i1 * 128);
        uint4 q2 = *reinterpret_cast<const uint4*>(base + (size_t)i2 * 128);
        uint4 q3 = *reinterpret_cast<const uint4*>(base + (size_t)i3 * 128);
        uint4 q4 = *reinterpret_cast<const uint4*>(base + (size_t)i4 * 128);
        uint4 q5 = *reinterpret_cast<const uint4*>(base + (size_t)i5 * 128);
        uint4 q6 = *reinterpret_cast<const uint4*>(base + (size_t)i6 * 128);
        uint4 q7 = *reinterpret_cast<const uint4*>(base + (size_t)i7 * 128);
        if (e+1 > last) q1 = z4;
        if (e+2 > last) q2 = z4;
        if (e+3 > last) q3 = z4;
        if (e+4 > last) q4 = z4;
        if (e+5 > last) q5 = z4;
        if (e+6 > last) q6 = z4;
        if (e+7 > last) q7 = z4;
        ACC8(q0) ACC8(q1) ACC8(q2) ACC8(q3) ACC8(q4) ACC8(q5) ACC8(q6) ACC8(q7)
    }
    int d = s1 - s0;
    float inv = (d > 0) ? 1.0f / (float)d : 0.0f;
    uint4 zq = *reinterpret_cast<const uint4*>(ylz + (size_t)v * 128 + 64 + li * 8);
    float4 o0, o1;
    o0.x = acc[0]*inv + bf16lo(zq.x);
    o0.y = acc[1]*inv + bf16hi(zq.x);
    o0.z = acc[2]*inv + bf16lo(zq.y);
    o0.w = acc[3]*inv + bf16hi(zq.y);
    o1.x = acc[4]*inv + bf16lo(zq.z);
    o1.y = acc[5]*inv + bf16hi(zq.z);
    o1.z = acc[6]*inv + bf16lo(zq.w);
    o1.w = acc[7]*inv + bf16hi(zq.w);
    *reinterpret_cast<float4*>(out + (size_t)v * 64 + li * 8) = o0;
    *reinterpret_cast<float4*>(out + (size_t)v * 64 + li * 8 + 4) = o1;
}

extern "C" void kernel_launch(void* const* d_in, const int* in_sizes, int n_in,
                              void* d_out, int out_size, void* d_ws, size_t ws_size,
                              hipStream_t stream)
{
    const float* x   = (const float*)d_in[0];
    const int*   ei  = (const int*)d_in[1];
    const float* Wl0 = (const float*)d_in[2];
    const float* Wr0 = (const float*)d_in[3];
    const float* b0  = (const float*)d_in[4];
    const float* Wl1 = (const float*)d_in[5];
    const float* Wr1 = (const float*)d_in[6];
    const float* b1  = (const float*)d_in[7];
    const float* Wl2 = (const float*)d_in[8];
    const float* Wr2 = (const float*)d_in[9];
    const float* b2  = (const float*)d_in[10];

    int N = in_sizes[0] / D;
    int E = in_sizes[1] / 2;
    const int* src = ei;
    const int* dst = ei + E;
    int NBK = (N + BKN - 1) >> BSH;      // 391 for N=100000

    char* ws = (char*)d_ws;
    size_t off = 0;
    auto alloc = [&](size_t bytes) -> void* {
        void* p = ws + off;
        off = (off + bytes + 255) & ~(size_t)255;
        return p;
    };
    int*      bfill  = (int*)alloc((size_t)NBK * 4);
    int*      roff   = (int*)alloc((size_t)N * 4);
    int*      rend   = (int*)alloc((size_t)N * 4);
    int*      csr    = (int*)alloc((size_t)NBK * CAPB * 4);
    unsigned short* ylz = (unsigned short*)alloc((size_t)N * 256 * 2);
    unsigned short* h0  = (unsigned short*)alloc((size_t)N * D * 2);
    unsigned short* h1  = (unsigned short*)alloc((size_t)N * D * 2);
    unsigned short* WT0 = (unsigned short*)alloc((size_t)256 * 128 * 2);
    unsigned short* WT1 = (unsigned short*)alloc((size_t)256 * 128 * 2);
    unsigned short* WT2 = (unsigned short*)alloc((size_t)128 * 128 * 2);
    // binbuf must NOT alias ylz now (gemm0 writes ylz while fill_bucket reads binbuf)
    uint32_t* binbuf = (uint32_t*)alloc((size_t)NBK * CAPB * 4);

    hipMemsetAsync(bfill, 0, (size_t)NBK * 4, stream);

    int nBin = (E + TILE - 1) / TILE;                    // 391
    int gG = (N + 127) / 128;                            // 782
    int gA = (N + 15) / 16;
    int gA2 = (N + 31) / 32;

    // K0: bin_edges ∥ wt_prep_all
    prep_and_bin<<<nBin + 320, 256, 0, stream>>>(
        src, dst, bfill, binbuf, E, NBK, nBin,
        Wl0, Wr0, Wl1, Wr1, Wl2, Wr2, WT0, WT1, WT2);

    // K1: fill_bucket ∥ layer-0 GEMM
    gemm0_fill<<<NBK + gG * 2, 256, 0, stream>>>(
        x, WT0, b0, ylz, N, binbuf, bfill, roff, rend, csr, NBK, gG);

    // layer 0 aggregate
    agg_relu<<<gA, 256, 0, stream>>>(ylz, roff, rend, csr, h0, N);
    // layer 1
    dense_gemm<256><<<dim3(gG, 2), 256, 0, stream>>>(h0, WT1, b1, ylz, N);
    agg_relu<<<gA, 256, 0, stream>>>(ylz, roff, rend, csr, h1, N);
    // layer 2 (64-wide)
    dense_gemm<128><<<dim3(gG, 1), 256, 0, stream>>>(h1, WT2, b2, ylz, N);
    agg_out64<<<gA2, 256, 0, stream>>>(ylz, roff, rend, csr, (float*)d_out, N);
}